// Round 4
// baseline (869.665 us; speedup 1.0000x reference)
//
#include <hip/hip_runtime.h>

// Problem constants (reference: N=100000, E=1600000, IN=128, OUT=256)
#define NODES 100000
#define EDGES 1600000
#define FIN   128
#define FOUT  256

typedef __bf16 bf16;
typedef __bf16 bf16x8 __attribute__((ext_vector_type(8)));
typedef __bf16 bf16x4 __attribute__((ext_vector_type(4)));
typedef float  f32x4  __attribute__((ext_vector_type(4)));

// ---------------- dtype detection ----------------
// flags[0] = 1 if float tensors are bf16, 0 if float32
// flags[1] = 1 if edge_index is int64, 0 if int32
__global__ __launch_bounds__(256) void detect_kernel(const void* __restrict__ x,
                                                     const int* __restrict__ ei,
                                                     int* __restrict__ flags) {
    __shared__ int s_f32_evidence;
    __shared__ int s_odd_nonzero;
    int t = threadIdx.x;
    if (t == 0) { s_f32_evidence = 0; s_odd_nonzero = 0; }
    __syncthreads();
    const bf16* xb = (const bf16*)x;
    int local_f32 = 0;
    for (int i = t; i < 4096; i += 256) {
        float v = fabsf((float)xb[i]);
        if (!(v < 1e4f)) local_f32 = 1;   // huge / inf / NaN -> data is f32
    }
    if (local_f32) atomicOr(&s_f32_evidence, 1);
    int local_odd = 0;
    for (int k = t; k < 1024; k += 256) {
        if (ei[2 * k + 1] != 0) local_odd = 1;   // nonzero odd word -> int32 data
    }
    if (local_odd) atomicOr(&s_odd_nonzero, 1);
    __syncthreads();
    if (t == 0) {
        flags[0] = s_f32_evidence ? 0 : 1;
        flags[1] = s_odd_nonzero ? 0 : 1;
    }
}

__device__ __forceinline__ int edge_at(const int* __restrict__ ei, int which, int i,
                                       int is64) {
    if (is64) return ei[2 * (which * EDGES + i)];   // little-endian low word
    return ei[which * EDGES + i];
}

// ---------------- degree / dinv ----------------
__global__ __launch_bounds__(256) void deg_count(const int* __restrict__ ei,
                                                 int* __restrict__ deg, int e,
                                                 const int* __restrict__ flags) {
    int i = blockIdx.x * 256 + threadIdx.x;
    if (i < e) {
        int d = edge_at(ei, 1, i, flags[1]);
        if (d >= 0 && d < NODES) atomicAdd(&deg[d], 1);
    }
}

__global__ __launch_bounds__(256) void deg_to_dinv(const int* __restrict__ deg,
                                                   float* __restrict__ dinv, int n) {
    int i = blockIdx.x * 256 + threadIdx.x;
    if (i < n) dinv[i] = rsqrtf((float)deg[i] + 1.0f);  // +1 = self-loop
}

// ---------------- exclusive scan (3 kernels) to build col_ptr ----------------
__global__ __launch_bounds__(1024) void scan1(const int* __restrict__ deg,
                                              int* __restrict__ col_ptr,
                                              int* __restrict__ blksum, int n) {
    __shared__ int sm[1024];
    int t = threadIdx.x;
    int i = blockIdx.x * 1024 + t;
    int v = (i < n) ? deg[i] : 0;
    sm[t] = v;
    __syncthreads();
    for (int off = 1; off < 1024; off <<= 1) {
        int u = (t >= off) ? sm[t - off] : 0;
        __syncthreads();
        sm[t] += u;
        __syncthreads();
    }
    if (i <= n) col_ptr[i] = sm[t] - v;
    if (t == 1023) blksum[blockIdx.x] = sm[t];
}

// parallel exclusive scan of <=128 block sums (1 block)
__global__ __launch_bounds__(128) void scan2(int* blk, int nblk) {
    __shared__ int sm[128];
    int t = threadIdx.x;
    int v = (t < nblk) ? blk[t] : 0;
    sm[t] = v;
    __syncthreads();
    for (int off = 1; off < 128; off <<= 1) {
        int u = (t >= off) ? sm[t - off] : 0;
        __syncthreads();
        sm[t] += u;
        __syncthreads();
    }
    if (t < nblk) blk[t] = sm[t] - v;
}

__global__ __launch_bounds__(256) void scan3(int* __restrict__ col_ptr,
                                             const int* __restrict__ blkoff,
                                             int* __restrict__ cursor, int n) {
    int i = blockIdx.x * 256 + threadIdx.x;
    if (i <= n) {
        int v = col_ptr[i] + blkoff[i >> 10];
        col_ptr[i] = v;
        if (i < n) cursor[i] = v;
    }
}

// ---------------- CSR fill: bucket src by dst ----------------
__global__ __launch_bounds__(256) void fill_csr(const int* __restrict__ ei,
                                                int* __restrict__ cursor,
                                                int* __restrict__ col_idx, int e,
                                                const int* __restrict__ flags) {
    int i = blockIdx.x * 256 + threadIdx.x;
    if (i < e) {
        int is64 = flags[1];
        int s = edge_at(ei, 0, i, is64);
        int d = edge_at(ei, 1, i, is64);
        if (s >= 0 && s < NODES && d >= 0 && d < NODES) {
            int pos = atomicAdd(&cursor[d], 1);
            col_idx[pos] = s;
        }
    }
}

// ---------------- pack all weights (MFMA B-frag order) + biases, one dispatch ----------------
// packed[((kt*16+ct)*64+lane)*8+j] = W[(kt*32+(lane>>4)*8+j)*256 + ct*16+(lane&15)]
__global__ __launch_bounds__(256) void pack_all(const void* __restrict__ W1,
                                                const void* __restrict__ W2,
                                                const void* __restrict__ Wp,
                                                const void* __restrict__ b1,
                                                const void* __restrict__ b2,
                                                const void* __restrict__ bp,
                                                bf16* __restrict__ W1p, bf16* __restrict__ W2p,
                                                bf16* __restrict__ Wpp, bf16* __restrict__ b1b,
                                                bf16* __restrict__ b2b, bf16* __restrict__ bpb,
                                                const int* __restrict__ flags) {
    int fl = flags[0];
    int b = blockIdx.x;
    if (b < 512) {
        const void* W; bf16* Wo; int idx;
        if (b < 128)      { W = W1; Wo = W1p; idx = b * 256 + threadIdx.x; }
        else if (b < 384) { W = W2; Wo = W2p; idx = (b - 128) * 256 + threadIdx.x; }
        else              { W = Wp; Wo = Wpp; idx = (b - 384) * 256 + threadIdx.x; }
        int j    = idx & 7;
        int lane = (idx >> 3) & 63;
        int ct   = (idx >> 9) & 15;
        int kt   = idx >> 13;
        int k = kt * 32 + (lane >> 4) * 8 + j;
        int n = ct * 16 + (lane & 15);
        Wo[idx] = fl ? ((const bf16*)W)[k * 256 + n]
                     : (bf16)(((const float*)W)[k * 256 + n]);
    } else {
        const void* bb; bf16* bo;
        if (b == 512)      { bb = b1; bo = b1b; }
        else if (b == 513) { bb = b2; bo = b2b; }
        else               { bb = bp; bo = bpb; }
        int i = threadIdx.x;
        bo[i] = fl ? ((const bf16*)bb)[i] : (bf16)(((const float*)bb)[i]);
    }
}

// ---------------- fused conv1+proj GEMM: reads x once ----------------
// out1[r,c] = (x@W1)[r,c] * dinv[r]          (bf16)
// out2[r,c] = (x@Wp)[r,c] + bp[c]            (dtype per flags -> d_out)
__global__ __launch_bounds__(256) void gemm_dual(const void* __restrict__ Av,
                                                 const bf16* __restrict__ Wp1,
                                                 const bf16* __restrict__ Wp2,
                                                 const float* __restrict__ dinv,
                                                 const bf16* __restrict__ bias2,
                                                 bf16* __restrict__ out1,
                                                 void* __restrict__ out2v,
                                                 const int* __restrict__ flags) {
    int a_f32 = (flags[0] == 0);
    int wave = threadIdx.x >> 6;
    int lane = threadIdx.x & 63;
    int row0 = blockIdx.x * 64 + wave * 16;

    int ar  = row0 + (lane & 15);
    int arc = ar < NODES ? ar : (NODES - 1);
    int ak  = (lane >> 4) * 8;

    f32x4 acc1[16], acc2[16];
    f32x4 z = {0.f, 0.f, 0.f, 0.f};
#pragma unroll
    for (int i = 0; i < 16; ++i) { acc1[i] = z; acc2[i] = z; }

    const bf16*  Ab = (const bf16*)Av  + (size_t)arc * FIN + ak;
    const float* Af = (const float*)Av + (size_t)arc * FIN + ak;

    for (int kt = 0; kt < 4; ++kt) {
        bf16x8 af;
        if (!a_f32) {
            af = *(const bf16x8*)(Ab + kt * 32);
        } else {
            const float* p = Af + kt * 32;
            f32x4 lo = *(const f32x4*)p;
            f32x4 hi = *(const f32x4*)(p + 4);
            af[0] = (bf16)lo[0]; af[1] = (bf16)lo[1]; af[2] = (bf16)lo[2]; af[3] = (bf16)lo[3];
            af[4] = (bf16)hi[0]; af[5] = (bf16)hi[1]; af[6] = (bf16)hi[2]; af[7] = (bf16)hi[3];
        }
        const bf16* wb1 = Wp1 + (size_t)kt * 8192 + lane * 8;
        const bf16* wb2 = Wp2 + (size_t)kt * 8192 + lane * 8;
#pragma unroll
        for (int ct = 0; ct < 16; ++ct) {
            acc1[ct] = __builtin_amdgcn_mfma_f32_16x16x32_bf16(
                af, *(const bf16x8*)(wb1 + ct * 512), acc1[ct], 0, 0, 0);
            acc2[ct] = __builtin_amdgcn_mfma_f32_16x16x32_bf16(
                af, *(const bf16x8*)(wb2 + ct * 512), acc2[ct], 0, 0, 0);
        }
    }

    int rbase = row0 + (lane >> 4) * 4;
    int cbase = lane & 15;
    int out2_f32 = a_f32;
#pragma unroll
    for (int r = 0; r < 4; ++r) {
        int row = rbase + r;
        if (row >= NODES) continue;
        float s = dinv[row];
#pragma unroll
        for (int ct = 0; ct < 16; ++ct) {
            int col = ct * 16 + cbase;
            size_t off = (size_t)row * 256 + col;
            out1[off] = (bf16)(acc1[ct][r] * s);
            float v2 = acc2[ct][r] + (float)bias2[col];
            if (out2_f32) ((float*)out2v)[off] = v2;
            else          ((bf16*)out2v)[off]  = (bf16)v2;
        }
    }
}

// ---------------- conv2 GEMM: 32 rows/wave, K=256 ----------------
// out[r,c] = (A@W2)[r,c] * dinv[r]  (bf16)
__global__ __launch_bounds__(256) void gemm_conv2(const bf16* __restrict__ A,
                                                  const bf16* __restrict__ Wp,
                                                  const float* __restrict__ dinv,
                                                  bf16* __restrict__ out) {
    int wave = threadIdx.x >> 6;
    int lane = threadIdx.x & 63;
    int row0 = blockIdx.x * 128 + wave * 32;

    int r0 = row0 + (lane & 15);
    int r1 = r0 + 16;
    int r0c = r0 < NODES ? r0 : (NODES - 1);
    int r1c = r1 < NODES ? r1 : (NODES - 1);
    int ak  = (lane >> 4) * 8;

    f32x4 acc[2][16];
    f32x4 z = {0.f, 0.f, 0.f, 0.f};
#pragma unroll
    for (int h = 0; h < 2; ++h)
#pragma unroll
        for (int i = 0; i < 16; ++i) acc[h][i] = z;

    const bf16* A0 = A + (size_t)r0c * FOUT + ak;
    const bf16* A1 = A + (size_t)r1c * FOUT + ak;

    for (int kt = 0; kt < 8; ++kt) {
        bf16x8 a0 = *(const bf16x8*)(A0 + kt * 32);
        bf16x8 a1 = *(const bf16x8*)(A1 + kt * 32);
        const bf16* wb = Wp + (size_t)kt * 8192 + lane * 8;
#pragma unroll
        for (int ct = 0; ct < 16; ++ct) {
            bf16x8 bfv = *(const bf16x8*)(wb + ct * 512);
            acc[0][ct] = __builtin_amdgcn_mfma_f32_16x16x32_bf16(a0, bfv, acc[0][ct], 0, 0, 0);
            acc[1][ct] = __builtin_amdgcn_mfma_f32_16x16x32_bf16(a1, bfv, acc[1][ct], 0, 0, 0);
        }
    }

    int cbase = lane & 15;
#pragma unroll
    for (int h = 0; h < 2; ++h) {
        int rbase = row0 + h * 16 + (lane >> 4) * 4;
#pragma unroll
        for (int r = 0; r < 4; ++r) {
            int row = rbase + r;
            if (row >= NODES) continue;
            float s = dinv[row];
#pragma unroll
            for (int ct = 0; ct < 16; ++ct) {
                int col = ct * 16 + cbase;
                out[(size_t)row * 256 + col] = (bf16)(acc[h][ct][r] * s);
            }
        }
    }
}

// ---------------- gather: one wave/node, preloaded indices, x4-unrolled row loads ----------------
// out[n] = relu(dinv[n]*(sum Xs[s] + Xs[n]) + bias [+ proj[n]])
__global__ __launch_bounds__(256) void gather_kernel(const int* __restrict__ col_ptr,
                                                     const int* __restrict__ col_idx,
                                                     const bf16* __restrict__ Xs,
                                                     const float* __restrict__ dinv,
                                                     const bf16* __restrict__ bias,
                                                     const void* __restrict__ proj,
                                                     void* __restrict__ outv,
                                                     const int* __restrict__ flags,
                                                     int io_dyn) {
    int io_f32 = io_dyn && (flags[0] == 0);
    int wid  = (int)((blockIdx.x * 256 + threadIdx.x) >> 6);
    int lane = threadIdx.x & 63;
    if (wid >= NODES) return;
    int beg = col_ptr[wid], end = col_ptr[wid + 1];
    int c = lane * 4;

    f32x4 acc = {0.f, 0.f, 0.f, 0.f};
    for (int chunk = beg; chunk < end; chunk += 64) {
        int cnt = end - chunk;
        if (cnt > 64) cnt = 64;
        int myidx = (lane < cnt) ? col_idx[chunk + lane] : 0;  // one coalesced load
        int j = 0;
        for (; j + 4 <= cnt; j += 4) {
            int s0 = __shfl(myidx, j);
            int s1 = __shfl(myidx, j + 1);
            int s2 = __shfl(myidx, j + 2);
            int s3 = __shfl(myidx, j + 3);
            bf16x4 v0 = *(const bf16x4*)(Xs + (size_t)s0 * 256 + c);
            bf16x4 v1 = *(const bf16x4*)(Xs + (size_t)s1 * 256 + c);
            bf16x4 v2 = *(const bf16x4*)(Xs + (size_t)s2 * 256 + c);
            bf16x4 v3 = *(const bf16x4*)(Xs + (size_t)s3 * 256 + c);
#pragma unroll
            for (int k = 0; k < 4; ++k)
                acc[k] += ((float)v0[k] + (float)v1[k]) + ((float)v2[k] + (float)v3[k]);
        }
        for (; j < cnt; ++j) {
            int s0 = __shfl(myidx, j);
            bf16x4 v0 = *(const bf16x4*)(Xs + (size_t)s0 * 256 + c);
#pragma unroll
            for (int k = 0; k < 4; ++k) acc[k] += (float)v0[k];
        }
    }

    bf16x4 selfv = *(const bf16x4*)(Xs + (size_t)wid * 256 + c);
    float di = dinv[wid];
    size_t base = (size_t)wid * 256 + c;

    f32x4 res;
#pragma unroll
    for (int k = 0; k < 4; ++k)
        res[k] = di * (acc[k] + (float)selfv[k]) + (float)bias[c + k];

    if (proj) {
        if (io_f32) {
            f32x4 pv = *(const f32x4*)((const float*)proj + base);
#pragma unroll
            for (int k = 0; k < 4; ++k) res[k] += pv[k];
        } else {
            bf16x4 pv = *(const bf16x4*)((const bf16*)proj + base);
#pragma unroll
            for (int k = 0; k < 4; ++k) res[k] += (float)pv[k];
        }
    }

    if (io_f32) {
        f32x4 o;
#pragma unroll
        for (int k = 0; k < 4; ++k) o[k] = fmaxf(res[k], 0.0f);
        *(f32x4*)((float*)outv + base) = o;
    } else {
        bf16x4 o;
#pragma unroll
        for (int k = 0; k < 4; ++k) o[k] = (bf16)fmaxf(res[k], 0.0f);
        *(bf16x4*)((bf16*)outv + base) = o;
    }
}

__global__ __launch_bounds__(256) void zero_out(bf16* out, int nelem) {
    int i = blockIdx.x * 256 + threadIdx.x;
    if (i < nelem) out[i] = (bf16)0.0f;
}

extern "C" void kernel_launch(void* const* d_in, const int* in_sizes, int n_in,
                              void* d_out, int out_size, void* d_ws, size_t ws_size,
                              hipStream_t stream) {
    const void* x   = d_in[0];
    const int*  ei  = (const int*)d_in[1];
    const void* W1  = d_in[2];
    const void* b1  = d_in[3];
    const void* W2  = d_in[4];
    const void* b2  = d_in[5];
    const void* Wp  = d_in[6];
    const void* bp  = d_in[7];

    const size_t NEEDED = 401408ull * 3 + 1024 + 1024 + 6400000 + 65536 + 131072 + 65536
                        + 1536 + 51200000ull * 2;  // ~110.3 MB (fit in R3)
    if (ws_size < NEEDED) {
        zero_out<<<(NODES * 256 + 255) / 256, 256, 0, stream>>>((bf16*)d_out, NODES * 256);
        return;
    }
    char* w = (char*)d_ws;
    int*   col_ptr = (int*)w;   w += 401408;   // N+1 ints
    int*   cursor  = (int*)w;   w += 401408;   // deg, then fill cursors
    float* dinv    = (float*)w; w += 401408;
    int*   blk     = (int*)w;   w += 1024;
    int*   flags   = (int*)w;   w += 1024;
    int*   col_idx = (int*)w;   w += 6400000;  // E ints
    bf16*  W1p     = (bf16*)w;  w += 65536;
    bf16*  W2p     = (bf16*)w;  w += 131072;
    bf16*  Wpp     = (bf16*)w;  w += 65536;
    bf16*  b1b     = (bf16*)w;  w += 512;
    bf16*  b2b     = (bf16*)w;  w += 512;
    bf16*  bpb     = (bf16*)w;  w += 512;
    bf16*  bufA    = (bf16*)w;  w += 51200000; // scaled XW
    bf16*  bufC    = (bf16*)w;  w += 51200000; // H1

    const int NBLK = (NODES + 1 + 1023) / 1024;  // 98

    // 0) detect dtypes
    detect_kernel<<<1, 256, 0, stream>>>(x, ei, flags);

    // 1) degree (into cursor) -> dinv
    hipMemsetAsync(cursor, 0, (size_t)NODES * 4, stream);
    deg_count<<<(EDGES + 255) / 256, 256, 0, stream>>>(ei, cursor, EDGES, flags);
    deg_to_dinv<<<(NODES + 255) / 256, 256, 0, stream>>>(cursor, dinv, NODES);

    // 2) CSR build
    scan1<<<NBLK, 1024, 0, stream>>>(cursor, col_ptr, blk, NODES);
    scan2<<<1, 128, 0, stream>>>(blk, NBLK);
    scan3<<<(NODES + 256) / 256, 256, 0, stream>>>(col_ptr, blk, cursor, NODES);
    fill_csr<<<(EDGES + 255) / 256, 256, 0, stream>>>(ei, cursor, col_idx, EDGES, flags);

    // 3) pack weights + biases (one dispatch)
    pack_all<<<515, 256, 0, stream>>>(W1, W2, Wp, b1, b2, bp,
                                      W1p, W2p, Wpp, b1b, b2b, bpb, flags);

    const int gather_grid = (NODES + 3) / 4;

    // 4) fused conv1 + proj: bufA = (x@W1)*dinv ; d_out = x@Wp + bp
    gemm_dual<<<(NODES + 63) / 64, 256, 0, stream>>>(x, W1p, Wpp, dinv, bpb,
                                                     bufA, d_out, flags);
    // 5) gather1: bufC = relu(dinv*(agg+self)+b1)
    gather_kernel<<<gather_grid, 256, 0, stream>>>(col_ptr, col_idx, bufA, dinv, b1b,
                                                   nullptr, bufC, flags, 0);
    // 6) conv2: bufA = (bufC@W2)*dinv
    gemm_conv2<<<(NODES + 127) / 128, 256, 0, stream>>>(bufC, W2p, dinv, bufA);
    // 7) gather2: d_out = relu(dinv*(agg+self) + b2 + proj)
    gather_kernel<<<gather_grid, 256, 0, stream>>>(col_ptr, col_idx, bufA, dinv, b2b,
                                                   d_out, d_out, flags, 1);
}

// Round 5
// 737.508 us; speedup vs baseline: 1.1792x; 1.1792x over previous
//
#include <hip/hip_runtime.h>

// Problem constants (reference: N=100000, E=1600000, IN=128, OUT=256)
#define NODES 100000
#define EDGES 1600000
#define FIN   128
#define FOUT  256

typedef __bf16 bf16;
typedef __bf16 bf16x8 __attribute__((ext_vector_type(8)));
typedef __bf16 bf16x4 __attribute__((ext_vector_type(4)));
typedef float  f32x4  __attribute__((ext_vector_type(4)));

// ---------------- dtype detection ----------------
// flags[0] = 1 if float tensors are bf16, 0 if float32
// flags[1] = 1 if edge_index is int64, 0 if int32
__global__ __launch_bounds__(256) void detect_kernel(const void* __restrict__ x,
                                                     const int* __restrict__ ei,
                                                     int* __restrict__ flags) {
    __shared__ int s_f32_evidence;
    __shared__ int s_odd_nonzero;
    int t = threadIdx.x;
    if (t == 0) { s_f32_evidence = 0; s_odd_nonzero = 0; }
    __syncthreads();
    const bf16* xb = (const bf16*)x;
    int local_f32 = 0;
    for (int i = t; i < 4096; i += 256) {
        float v = fabsf((float)xb[i]);
        if (!(v < 1e4f)) local_f32 = 1;   // huge / inf / NaN -> data is f32
    }
    if (local_f32) atomicOr(&s_f32_evidence, 1);
    int local_odd = 0;
    for (int k = t; k < 1024; k += 256) {
        if (ei[2 * k + 1] != 0) local_odd = 1;   // nonzero odd word -> int32 data
    }
    if (local_odd) atomicOr(&s_odd_nonzero, 1);
    __syncthreads();
    if (t == 0) {
        flags[0] = s_f32_evidence ? 0 : 1;
        flags[1] = s_odd_nonzero ? 0 : 1;
    }
}

__device__ __forceinline__ int edge_at(const int* __restrict__ ei, int which, int i,
                                       int is64) {
    if (is64) return ei[2 * (which * EDGES + i)];   // little-endian low word
    return ei[which * EDGES + i];
}

// ---------------- degree / dinv ----------------
__global__ __launch_bounds__(256) void deg_count(const int* __restrict__ ei,
                                                 int* __restrict__ deg, int e,
                                                 const int* __restrict__ flags) {
    int i = blockIdx.x * 256 + threadIdx.x;
    if (i < e) {
        int d = edge_at(ei, 1, i, flags[1]);
        if (d >= 0 && d < NODES) atomicAdd(&deg[d], 1);
    }
}

__global__ __launch_bounds__(256) void deg_to_dinv(const int* __restrict__ deg,
                                                   float* __restrict__ dinv, int n) {
    int i = blockIdx.x * 256 + threadIdx.x;
    if (i < n) dinv[i] = rsqrtf((float)deg[i] + 1.0f);  // +1 = self-loop
}

// ---------------- exclusive scan (3 kernels) to build col_ptr ----------------
__global__ __launch_bounds__(1024) void scan1(const int* __restrict__ deg,
                                              int* __restrict__ col_ptr,
                                              int* __restrict__ blksum, int n) {
    __shared__ int sm[1024];
    int t = threadIdx.x;
    int i = blockIdx.x * 1024 + t;
    int v = (i < n) ? deg[i] : 0;
    sm[t] = v;
    __syncthreads();
    for (int off = 1; off < 1024; off <<= 1) {
        int u = (t >= off) ? sm[t - off] : 0;
        __syncthreads();
        sm[t] += u;
        __syncthreads();
    }
    if (i <= n) col_ptr[i] = sm[t] - v;
    if (t == 1023) blksum[blockIdx.x] = sm[t];
}

__global__ __launch_bounds__(128) void scan2(int* blk, int nblk) {
    __shared__ int sm[128];
    int t = threadIdx.x;
    int v = (t < nblk) ? blk[t] : 0;
    sm[t] = v;
    __syncthreads();
    for (int off = 1; off < 128; off <<= 1) {
        int u = (t >= off) ? sm[t - off] : 0;
        __syncthreads();
        sm[t] += u;
        __syncthreads();
    }
    if (t < nblk) blk[t] = sm[t] - v;
}

__global__ __launch_bounds__(256) void scan3(int* __restrict__ col_ptr,
                                             const int* __restrict__ blkoff,
                                             int* __restrict__ cursor, int n) {
    int i = blockIdx.x * 256 + threadIdx.x;
    if (i <= n) {
        int v = col_ptr[i] + blkoff[i >> 10];
        col_ptr[i] = v;
        if (i < n) cursor[i] = v;
    }
}

// ---------------- CSR fill: bucket src by dst ----------------
__global__ __launch_bounds__(256) void fill_csr(const int* __restrict__ ei,
                                                int* __restrict__ cursor,
                                                int* __restrict__ col_idx, int e,
                                                const int* __restrict__ flags) {
    int i = blockIdx.x * 256 + threadIdx.x;
    if (i < e) {
        int is64 = flags[1];
        int s = edge_at(ei, 0, i, is64);
        int d = edge_at(ei, 1, i, is64);
        if (s >= 0 && s < NODES && d >= 0 && d < NODES) {
            int pos = atomicAdd(&cursor[d], 1);
            col_idx[pos] = s;
        }
    }
}

// ---------------- pack all weights (MFMA B-frag order) + biases, one dispatch ----------------
// packed[((kt*16+ct)*64+lane)*8+j] = W[(kt*32+(lane>>4)*8+j)*256 + ct*16+(lane&15)]
__global__ __launch_bounds__(256) void pack_all(const void* __restrict__ W1,
                                                const void* __restrict__ W2,
                                                const void* __restrict__ Wp,
                                                const void* __restrict__ b1,
                                                const void* __restrict__ b2,
                                                const void* __restrict__ bp,
                                                bf16* __restrict__ W1p, bf16* __restrict__ W2p,
                                                bf16* __restrict__ Wpp, bf16* __restrict__ b1b,
                                                bf16* __restrict__ b2b, bf16* __restrict__ bpb,
                                                const int* __restrict__ flags) {
    int fl = flags[0];
    int b = blockIdx.x;
    if (b < 512) {
        const void* W; bf16* Wo; int idx;
        if (b < 128)      { W = W1; Wo = W1p; idx = b * 256 + threadIdx.x; }
        else if (b < 384) { W = W2; Wo = W2p; idx = (b - 128) * 256 + threadIdx.x; }
        else              { W = Wp; Wo = Wpp; idx = (b - 384) * 256 + threadIdx.x; }
        int j    = idx & 7;
        int lane = (idx >> 3) & 63;
        int ct   = (idx >> 9) & 15;
        int kt   = idx >> 13;
        int k = kt * 32 + (lane >> 4) * 8 + j;
        int n = ct * 16 + (lane & 15);
        Wo[idx] = fl ? ((const bf16*)W)[k * 256 + n]
                     : (bf16)(((const float*)W)[k * 256 + n]);
    } else {
        const void* bb; bf16* bo;
        if (b == 512)      { bb = b1; bo = b1b; }
        else if (b == 513) { bb = b2; bo = b2b; }
        else               { bb = bp; bo = bpb; }
        int i = threadIdx.x;
        bo[i] = fl ? ((const bf16*)bb)[i] : (bf16)(((const float*)bb)[i]);
    }
}

// ---------------- GEMM tile: block = 64 rows x 256 cols, wave = 64 rows x 64 cols ----------------
// out[r,c] = (A[nrows,K] @ W[K,256])[r,c] (*dinv[r] if dinv) (+bias[c] if bias), bf16 out
// acc[4][4] = 64 VGPRs -> ~4 waves/SIMD occupancy; 8 loads per 16 MFMAs
__global__ __launch_bounds__(256) void gemm_tile(const void* __restrict__ Av,
                                                 const bf16* __restrict__ Wpk,
                                                 int K, int nrows,
                                                 const float* __restrict__ dinv,
                                                 const bf16* __restrict__ bias,
                                                 bf16* __restrict__ out,
                                                 const int* __restrict__ flags,
                                                 int a_dyn) {
    int a_f32 = a_dyn && (flags[0] == 0);
    int wave = threadIdx.x >> 6;
    int lane = threadIdx.x & 63;
    int row0 = blockIdx.x * 64;
    int lr = lane & 15;
    int lk = (lane >> 4) * 8;

    int arow[4];
#pragma unroll
    for (int rf = 0; rf < 4; ++rf) {
        int r = row0 + rf * 16 + lr;
        arow[rf] = r < nrows ? r : (nrows - 1);
    }

    f32x4 acc[4][4];
    f32x4 z = {0.f, 0.f, 0.f, 0.f};
#pragma unroll
    for (int i = 0; i < 4; ++i)
#pragma unroll
        for (int j = 0; j < 4; ++j) acc[i][j] = z;

    int ktiles = K >> 5;
    for (int kt = 0; kt < ktiles; ++kt) {
        bf16x8 af[4];
        if (!a_f32) {
            const bf16* Ab = (const bf16*)Av + kt * 32 + lk;
#pragma unroll
            for (int rf = 0; rf < 4; ++rf)
                af[rf] = *(const bf16x8*)(Ab + (size_t)arow[rf] * K);
        } else {
            const float* Af = (const float*)Av + kt * 32 + lk;
#pragma unroll
            for (int rf = 0; rf < 4; ++rf) {
                const float* p = Af + (size_t)arow[rf] * K;
                f32x4 lo = *(const f32x4*)p;
                f32x4 hi = *(const f32x4*)(p + 4);
                af[rf][0] = (bf16)lo[0]; af[rf][1] = (bf16)lo[1];
                af[rf][2] = (bf16)lo[2]; af[rf][3] = (bf16)lo[3];
                af[rf][4] = (bf16)hi[0]; af[rf][5] = (bf16)hi[1];
                af[rf][6] = (bf16)hi[2]; af[rf][7] = (bf16)hi[3];
            }
        }
        const bf16* wb = Wpk + ((size_t)(kt * 16 + wave * 4) * 64 + lane) * 8;
        bf16x8 bfv[4];
#pragma unroll
        for (int cf = 0; cf < 4; ++cf)
            bfv[cf] = *(const bf16x8*)(wb + cf * 512);
#pragma unroll
        for (int rf = 0; rf < 4; ++rf)
#pragma unroll
            for (int cf = 0; cf < 4; ++cf)
                acc[rf][cf] = __builtin_amdgcn_mfma_f32_16x16x32_bf16(
                    af[rf], bfv[cf], acc[rf][cf], 0, 0, 0);
    }

    // C/D layout: col = ct*16 + (lane&15), row = rf*16 + (lane>>4)*4 + r
    int rb = (lane >> 4) * 4;
#pragma unroll
    for (int rf = 0; rf < 4; ++rf) {
#pragma unroll
        for (int r = 0; r < 4; ++r) {
            int row = row0 + rf * 16 + rb + r;
            if (row >= nrows) continue;
            float s = dinv ? dinv[row] : 1.0f;
#pragma unroll
            for (int cf = 0; cf < 4; ++cf) {
                int col = wave * 64 + cf * 16 + lr;
                float v = acc[rf][cf][r] * s;
                if (bias) v += (float)bias[col];
                out[(size_t)row * 256 + col] = (bf16)v;
            }
        }
    }
}

// ---------------- gather: one wave/node, preloaded indices, x4-unrolled row loads ----------------
// out[n] = relu(dinv[n]*(sum Xs[s] + Xs[n]) + bias [+ proj[n]])   proj: bf16 or null
__global__ __launch_bounds__(256) void gather_kernel(const int* __restrict__ col_ptr,
                                                     const int* __restrict__ col_idx,
                                                     const bf16* __restrict__ Xs,
                                                     const float* __restrict__ dinv,
                                                     const bf16* __restrict__ bias,
                                                     const bf16* __restrict__ proj,
                                                     void* __restrict__ outv,
                                                     const int* __restrict__ flags,
                                                     int out_dyn) {
    int out_f32 = out_dyn && (flags[0] == 0);
    int wid  = (int)((blockIdx.x * 256 + threadIdx.x) >> 6);
    int lane = threadIdx.x & 63;
    if (wid >= NODES) return;
    int beg = col_ptr[wid], end = col_ptr[wid + 1];
    int c = lane * 4;

    f32x4 acc = {0.f, 0.f, 0.f, 0.f};
    for (int chunk = beg; chunk < end; chunk += 64) {
        int cnt = end - chunk;
        if (cnt > 64) cnt = 64;
        int myidx = (lane < cnt) ? col_idx[chunk + lane] : 0;  // one coalesced load
        int j = 0;
        for (; j + 4 <= cnt; j += 4) {
            int s0 = __shfl(myidx, j);
            int s1 = __shfl(myidx, j + 1);
            int s2 = __shfl(myidx, j + 2);
            int s3 = __shfl(myidx, j + 3);
            bf16x4 v0 = *(const bf16x4*)(Xs + (size_t)s0 * 256 + c);
            bf16x4 v1 = *(const bf16x4*)(Xs + (size_t)s1 * 256 + c);
            bf16x4 v2 = *(const bf16x4*)(Xs + (size_t)s2 * 256 + c);
            bf16x4 v3 = *(const bf16x4*)(Xs + (size_t)s3 * 256 + c);
#pragma unroll
            for (int k = 0; k < 4; ++k)
                acc[k] += ((float)v0[k] + (float)v1[k]) + ((float)v2[k] + (float)v3[k]);
        }
        for (; j < cnt; ++j) {
            int s0 = __shfl(myidx, j);
            bf16x4 v0 = *(const bf16x4*)(Xs + (size_t)s0 * 256 + c);
#pragma unroll
            for (int k = 0; k < 4; ++k) acc[k] += (float)v0[k];
        }
    }

    bf16x4 selfv = *(const bf16x4*)(Xs + (size_t)wid * 256 + c);
    float di = dinv[wid];
    size_t base = (size_t)wid * 256 + c;

    f32x4 res;
#pragma unroll
    for (int k = 0; k < 4; ++k)
        res[k] = di * (acc[k] + (float)selfv[k]) + (float)bias[c + k];

    if (proj) {
        bf16x4 pv = *(const bf16x4*)(proj + base);
#pragma unroll
        for (int k = 0; k < 4; ++k) res[k] += (float)pv[k];
    }

    if (out_f32) {
        f32x4 o;
#pragma unroll
        for (int k = 0; k < 4; ++k) o[k] = fmaxf(res[k], 0.0f);
        *(f32x4*)((float*)outv + base) = o;
    } else {
        bf16x4 o;
#pragma unroll
        for (int k = 0; k < 4; ++k) o[k] = (bf16)fmaxf(res[k], 0.0f);
        *(bf16x4*)((bf16*)outv + base) = o;
    }
}

__global__ __launch_bounds__(256) void zero_out(bf16* out, int nelem) {
    int i = blockIdx.x * 256 + threadIdx.x;
    if (i < nelem) out[i] = (bf16)0.0f;
}

extern "C" void kernel_launch(void* const* d_in, const int* in_sizes, int n_in,
                              void* d_out, int out_size, void* d_ws, size_t ws_size,
                              hipStream_t stream) {
    const void* x   = d_in[0];
    const int*  ei  = (const int*)d_in[1];
    const void* W1  = d_in[2];
    const void* b1  = d_in[3];
    const void* W2  = d_in[4];
    const void* b2  = d_in[5];
    const void* Wp  = d_in[6];
    const void* bp  = d_in[7];

    const size_t NEEDED = 401408ull * 3 + 1024 + 1024 + 6400000 + 65536 + 131072 + 65536
                        + 1536 + 51200000ull * 2;  // ~110.3 MB (fit in R3/R4)
    if (ws_size < NEEDED) {
        zero_out<<<(NODES * 256 + 255) / 256, 256, 0, stream>>>((bf16*)d_out, NODES * 256);
        return;
    }
    char* w = (char*)d_ws;
    int*   col_ptr = (int*)w;   w += 401408;   // N+1 ints
    int*   cursor  = (int*)w;   w += 401408;   // deg, then fill cursors
    float* dinv    = (float*)w; w += 401408;
    int*   blk     = (int*)w;   w += 1024;
    int*   flags   = (int*)w;   w += 1024;
    int*   col_idx = (int*)w;   w += 6400000;  // E ints
    bf16*  W1p     = (bf16*)w;  w += 65536;
    bf16*  W2p     = (bf16*)w;  w += 131072;
    bf16*  Wpp     = (bf16*)w;  w += 65536;
    bf16*  b1b     = (bf16*)w;  w += 512;
    bf16*  b2b     = (bf16*)w;  w += 512;
    bf16*  bpb     = (bf16*)w;  w += 512;
    bf16*  bufA    = (bf16*)w;  w += 51200000; // scaled XW / conv2 result
    bf16*  bufC    = (bf16*)w;  w += 51200000; // H1, then proj

    const int NBLK = (NODES + 1 + 1023) / 1024;  // 98

    // 0) detect dtypes
    detect_kernel<<<1, 256, 0, stream>>>(x, ei, flags);

    // 1) degree (into cursor) -> dinv
    hipMemsetAsync(cursor, 0, (size_t)NODES * 4, stream);
    deg_count<<<(EDGES + 255) / 256, 256, 0, stream>>>(ei, cursor, EDGES, flags);
    deg_to_dinv<<<(NODES + 255) / 256, 256, 0, stream>>>(cursor, dinv, NODES);

    // 2) CSR build
    scan1<<<NBLK, 1024, 0, stream>>>(cursor, col_ptr, blk, NODES);
    scan2<<<1, 128, 0, stream>>>(blk, NBLK);
    scan3<<<(NODES + 256) / 256, 256, 0, stream>>>(col_ptr, blk, cursor, NODES);
    fill_csr<<<(EDGES + 255) / 256, 256, 0, stream>>>(ei, cursor, col_idx, EDGES, flags);

    // 3) pack weights + biases (one dispatch)
    pack_all<<<515, 256, 0, stream>>>(W1, W2, Wp, b1, b2, bp,
                                      W1p, W2p, Wpp, b1b, b2b, bpb, flags);

    const int gemm_grid   = (NODES + 63) / 64;
    const int gather_grid = (NODES + 3) / 4;

    // 4) conv1: bufA = (x@W1)*dinv
    gemm_tile<<<gemm_grid, 256, 0, stream>>>(x, W1p, FIN, NODES, dinv, nullptr,
                                             bufA, flags, 1);
    // 5) gather1: bufC = relu(dinv*(agg+self)+b1)
    gather_kernel<<<gather_grid, 256, 0, stream>>>(col_ptr, col_idx, bufA, dinv, b1b,
                                                   nullptr, bufC, flags, 0);
    // 6) conv2: bufA = (bufC@W2)*dinv
    gemm_tile<<<gemm_grid, 256, 0, stream>>>(bufC, W2p, FOUT, NODES, dinv, nullptr,
                                             bufA, flags, 0);
    // 7) proj: bufC = x@Wp + bp   (bufC free after conv2)
    gemm_tile<<<gemm_grid, 256, 0, stream>>>(x, Wpp, FIN, NODES, nullptr, bpb,
                                             bufC, flags, 1);
    // 8) gather2: d_out = relu(dinv*(agg+self) + b2 + proj)
    gather_kernel<<<gather_grid, 256, 0, stream>>>(col_ptr, col_idx, bufA, dinv, b2b,
                                                   bufC, d_out, flags, 1);
}

// Round 6
// 667.004 us; speedup vs baseline: 1.3038x; 1.1057x over previous
//
#include <hip/hip_runtime.h>

// Problem constants (reference: N=100000, E=1600000, IN=128, OUT=256)
#define NODES 100000
#define EDGES 1600000
#define FIN   128
#define FOUT  256
#define NBUCK 196   // ceil(NODES/512), bucket = dst >> 9

typedef __bf16 bf16;
typedef __bf16 bf16x8 __attribute__((ext_vector_type(8)));
typedef __bf16 bf16x4 __attribute__((ext_vector_type(4)));
typedef __bf16 bf16x2 __attribute__((ext_vector_type(2)));
typedef float  f32x4  __attribute__((ext_vector_type(4)));

// ---------------- dtype detection ----------------
// flags[0] = 1 if float tensors are bf16, 0 if float32
// flags[1] = 1 if edge_index is int64, 0 if int32
__global__ __launch_bounds__(256) void detect_kernel(const void* __restrict__ x,
                                                     const int* __restrict__ ei,
                                                     int* __restrict__ flags) {
    __shared__ int s_f32_evidence;
    __shared__ int s_odd_nonzero;
    int t = threadIdx.x;
    if (t == 0) { s_f32_evidence = 0; s_odd_nonzero = 0; }
    __syncthreads();
    const bf16* xb = (const bf16*)x;
    int local_f32 = 0;
    for (int i = t; i < 4096; i += 256) {
        float v = fabsf((float)xb[i]);
        if (!(v < 1e4f)) local_f32 = 1;   // huge / inf / NaN -> data is f32
    }
    if (local_f32) atomicOr(&s_f32_evidence, 1);
    int local_odd = 0;
    for (int k = t; k < 1024; k += 256) {
        if (ei[2 * k + 1] != 0) local_odd = 1;   // nonzero odd word -> int32 data
    }
    if (local_odd) atomicOr(&s_odd_nonzero, 1);
    __syncthreads();
    if (t == 0) {
        flags[0] = s_f32_evidence ? 0 : 1;
        flags[1] = s_odd_nonzero ? 0 : 1;
    }
}

__device__ __forceinline__ int edge_at(const int* __restrict__ ei, int which, int i,
                                       int is64) {
    if (is64) return ei[2 * (which * EDGES + i)];   // little-endian low word
    return ei[which * EDGES + i];
}

// ---------------- degree count + bucket histogram ----------------
__global__ __launch_bounds__(512) void deg_count(const int* __restrict__ ei,
                                                 int* __restrict__ deg,
                                                 int* __restrict__ bhist,
                                                 const int* __restrict__ flags) {
    __shared__ int lh[256];
    int t = threadIdx.x;
    if (t < 256) lh[t] = 0;
    __syncthreads();
    int i = blockIdx.x * 512 + t;
    if (i < EDGES) {
        int is64 = flags[1];
        int s = edge_at(ei, 0, i, is64);
        int d = edge_at(ei, 1, i, is64);
        if (s >= 0 && s < NODES && d >= 0 && d < NODES) {
            atomicAdd(&deg[d], 1);
            atomicAdd(&lh[d >> 9], 1);
        }
    }
    __syncthreads();
    if (t < NBUCK && lh[t] > 0) atomicAdd(&bhist[t], lh[t]);
}

__global__ __launch_bounds__(256) void deg_to_dinv(const int* __restrict__ deg,
                                                   float* __restrict__ dinv, int n) {
    int i = blockIdx.x * 256 + threadIdx.x;
    if (i < n) dinv[i] = rsqrtf((float)deg[i] + 1.0f);  // +1 = self-loop
}

// ---------------- exclusive scan (3 kernels) for col_ptr ----------------
__global__ __launch_bounds__(1024) void scan1(const int* __restrict__ deg,
                                              int* __restrict__ col_ptr,
                                              int* __restrict__ blksum, int n) {
    __shared__ int sm[1024];
    int t = threadIdx.x;
    int i = blockIdx.x * 1024 + t;
    int v = (i < n) ? deg[i] : 0;
    sm[t] = v;
    __syncthreads();
    for (int off = 1; off < 1024; off <<= 1) {
        int u = (t >= off) ? sm[t - off] : 0;
        __syncthreads();
        sm[t] += u;
        __syncthreads();
    }
    if (i <= n) col_ptr[i] = sm[t] - v;
    if (t == 1023) blksum[blockIdx.x] = sm[t];
}

__global__ __launch_bounds__(128) void scan2(int* blk, int nblk) {
    __shared__ int sm[128];
    int t = threadIdx.x;
    int v = (t < nblk) ? blk[t] : 0;
    sm[t] = v;
    __syncthreads();
    for (int off = 1; off < 128; off <<= 1) {
        int u = (t >= off) ? sm[t - off] : 0;
        __syncthreads();
        sm[t] += u;
        __syncthreads();
    }
    if (t < nblk) blk[t] = sm[t] - v;
}

__global__ __launch_bounds__(256) void scan3(int* __restrict__ col_ptr,
                                             const int* __restrict__ blkoff, int n) {
    int i = blockIdx.x * 256 + threadIdx.x;
    if (i <= n) col_ptr[i] += blkoff[i >> 10];
}

// ---------------- bucket scan: bhist -> bbase (exclusive, +total), bcur ----------------
__global__ __launch_bounds__(256) void bucket_scan(const int* __restrict__ bhist,
                                                   int* __restrict__ bbase,
                                                   int* __restrict__ bcur) {
    __shared__ int sm[256];
    int t = threadIdx.x;
    int v = (t < NBUCK) ? bhist[t] : 0;
    sm[t] = v;
    __syncthreads();
    for (int off = 1; off < 256; off <<= 1) {
        int u = (t >= off) ? sm[t - off] : 0;
        __syncthreads();
        sm[t] += u;
        __syncthreads();
    }
    if (t < NBUCK) {
        int ex = sm[t] - v;
        bbase[t] = ex;
        bcur[t]  = ex;
        if (t == NBUCK - 1) bbase[NBUCK] = sm[t];
    }
}

// ---------------- partition: bucket-group edges via LDS staging ----------------
// out: pairs[] grouped by bucket (dst>>9); coalesced segment writes
#define EPB 4096
__global__ __launch_bounds__(256) void partition_edges(const int* __restrict__ ei,
                                                       int* __restrict__ bcur,
                                                       uint2* __restrict__ pairs,
                                                       const int* __restrict__ flags) {
    __shared__ int lh[256], sc[256], lst[256], lcu[256], gb[256];
    __shared__ uint2 stage[EPB];
    int t = threadIdx.x;
    int base = blockIdx.x * EPB;
    int is64 = flags[1];

    lh[t] = 0;
    __syncthreads();

    int es[16], ed[16];
#pragma unroll
    for (int j = 0; j < 16; ++j) {
        int i = base + j * 256 + t;
        int s = -1, d = -1;
        if (i < EDGES) {
            s = edge_at(ei, 0, i, is64);
            d = edge_at(ei, 1, i, is64);
            if (s < 0 || s >= NODES || d < 0 || d >= NODES) d = -1;
        }
        es[j] = s; ed[j] = d;
        if (d >= 0) atomicAdd(&lh[d >> 9], 1);
    }
    __syncthreads();
    sc[t] = lh[t];
    __syncthreads();
    for (int off = 1; off < 256; off <<= 1) {
        int u = (t >= off) ? sc[t - off] : 0;
        __syncthreads();
        sc[t] += u;
        __syncthreads();
    }
    int start = sc[t] - lh[t];
    lst[t] = start;
    lcu[t] = start;
    __syncthreads();
#pragma unroll
    for (int j = 0; j < 16; ++j) {
        if (ed[j] >= 0) {
            int p = atomicAdd(&lcu[ed[j] >> 9], 1);
            stage[p] = make_uint2((unsigned)es[j], (unsigned)ed[j]);
        }
    }
    __syncthreads();
    if (t < NBUCK && lh[t] > 0) gb[t] = atomicAdd(&bcur[t], lh[t]);
    __syncthreads();
    int nval = sc[255];
    for (int slot = t; slot < nval; slot += 256) {
        uint2 e = stage[slot];
        int b = (int)(e.y >> 9);
        pairs[(size_t)gb[b] + (slot - lst[b])] = e;
    }
}

// ---------------- fine fill: per-bucket scatter, L2-resident window ----------------
__global__ __launch_bounds__(512) void fine_fill(const uint2* __restrict__ pairs,
                                                 const int* __restrict__ bbase,
                                                 const int* __restrict__ col_ptr,
                                                 int* __restrict__ col_idx) {
    __shared__ int lcur[512];
    int b = blockIdx.x;
    int t = threadIdx.x;
    int node = (b << 9) + t;
    lcur[t] = (node < NODES) ? col_ptr[node] : 0;
    __syncthreads();
    int beg = bbase[b], end = bbase[b + 1];
    for (int i = beg + t; i < end; i += 512) {
        uint2 e = pairs[i];
        int pos = atomicAdd(&lcur[e.y & 511], 1);
        col_idx[pos] = (int)e.x;
    }
}

// ---------------- pack all weights (MFMA B-frag order) + biases ----------------
__global__ __launch_bounds__(256) void pack_all(const void* __restrict__ W1,
                                                const void* __restrict__ W2,
                                                const void* __restrict__ Wp,
                                                const void* __restrict__ b1,
                                                const void* __restrict__ b2,
                                                const void* __restrict__ bp,
                                                bf16* __restrict__ W1p, bf16* __restrict__ W2p,
                                                bf16* __restrict__ Wpp, bf16* __restrict__ b1b,
                                                bf16* __restrict__ b2b, bf16* __restrict__ bpb,
                                                const int* __restrict__ flags) {
    int fl = flags[0];
    int b = blockIdx.x;
    if (b < 512) {
        const void* W; bf16* Wo; int idx;
        if (b < 128)      { W = W1; Wo = W1p; idx = b * 256 + threadIdx.x; }
        else if (b < 384) { W = W2; Wo = W2p; idx = (b - 128) * 256 + threadIdx.x; }
        else              { W = Wp; Wo = Wpp; idx = (b - 384) * 256 + threadIdx.x; }
        int j    = idx & 7;
        int lane = (idx >> 3) & 63;
        int ct   = (idx >> 9) & 15;
        int kt   = idx >> 13;
        int k = kt * 32 + (lane >> 4) * 8 + j;
        int n = ct * 16 + (lane & 15);
        Wo[idx] = fl ? ((const bf16*)W)[k * 256 + n]
                     : (bf16)(((const float*)W)[k * 256 + n]);
    } else {
        const void* bb; bf16* bo;
        if (b == 512)      { bb = b1; bo = b1b; }
        else if (b == 513) { bb = b2; bo = b2b; }
        else               { bb = bp; bo = bpb; }
        int i = threadIdx.x;
        bo[i] = fl ? ((const bf16*)bb)[i] : (bf16)(((const float*)bb)[i]);
    }
}

// ---------------- proj GEMM (K=128) + emit Xs = dinv*x (bf16) ----------------
// proj[r,c] = (x@Wp)[r,c] + bp[c]  -> d_out (dtype per flags)
__global__ __launch_bounds__(256) void gemm_proj(const void* __restrict__ Av,
                                                 const bf16* __restrict__ Wpk,
                                                 const float* __restrict__ dinv,
                                                 const bf16* __restrict__ bias,
                                                 void* __restrict__ outv,
                                                 bf16* __restrict__ Xs,
                                                 const int* __restrict__ flags) {
    int a_f32 = (flags[0] == 0);
    int wave = threadIdx.x >> 6;
    int lane = threadIdx.x & 63;
    int row0 = blockIdx.x * 64;
    int lr = lane & 15;
    int lk = (lane >> 4) * 8;

    int arow[4];
    float di4[4];
#pragma unroll
    for (int rf = 0; rf < 4; ++rf) {
        int r = row0 + rf * 16 + lr;
        arow[rf] = r < NODES ? r : (NODES - 1);
        di4[rf] = dinv[arow[rf]];
    }

    f32x4 acc[4][4];
    f32x4 z = {0.f, 0.f, 0.f, 0.f};
#pragma unroll
    for (int i = 0; i < 4; ++i)
#pragma unroll
        for (int j = 0; j < 4; ++j) acc[i][j] = z;

    for (int kt = 0; kt < 4; ++kt) {
        bf16x8 af[4];
        if (!a_f32) {
            const bf16* Ab = (const bf16*)Av + kt * 32 + lk;
#pragma unroll
            for (int rf = 0; rf < 4; ++rf)
                af[rf] = *(const bf16x8*)(Ab + (size_t)arow[rf] * FIN);
        } else {
            const float* Af = (const float*)Av + kt * 32 + lk;
#pragma unroll
            for (int rf = 0; rf < 4; ++rf) {
                const float* p = Af + (size_t)arow[rf] * FIN;
                f32x4 lo = *(const f32x4*)p;
                f32x4 hi = *(const f32x4*)(p + 4);
                af[rf][0] = (bf16)lo[0]; af[rf][1] = (bf16)lo[1];
                af[rf][2] = (bf16)lo[2]; af[rf][3] = (bf16)lo[3];
                af[rf][4] = (bf16)hi[0]; af[rf][5] = (bf16)hi[1];
                af[rf][6] = (bf16)hi[2]; af[rf][7] = (bf16)hi[3];
            }
        }
        // emit Xs tile: Xs[row, kt*32+lk .. +8] = dinv[row] * x
#pragma unroll
        for (int rf = 0; rf < 4; ++rf) {
            bf16x8 xsv;
#pragma unroll
            for (int j = 0; j < 8; ++j) xsv[j] = (bf16)(di4[rf] * (float)af[rf][j]);
            *(bf16x8*)(Xs + (size_t)arow[rf] * FIN + kt * 32 + lk) = xsv;
        }
        const bf16* wb = Wpk + ((size_t)(kt * 16 + wave * 4) * 64 + lane) * 8;
        bf16x8 bfv[4];
#pragma unroll
        for (int cf = 0; cf < 4; ++cf)
            bfv[cf] = *(const bf16x8*)(wb + cf * 512);
#pragma unroll
        for (int rf = 0; rf < 4; ++rf)
#pragma unroll
            for (int cf = 0; cf < 4; ++cf)
                acc[rf][cf] = __builtin_amdgcn_mfma_f32_16x16x32_bf16(
                    af[rf], bfv[cf], acc[rf][cf], 0, 0, 0);
    }

    int rb = (lane >> 4) * 4;
    int out_f32 = a_f32;
#pragma unroll
    for (int rf = 0; rf < 4; ++rf) {
#pragma unroll
        for (int r = 0; r < 4; ++r) {
            int row = row0 + rf * 16 + rb + r;
            if (row >= NODES) continue;
#pragma unroll
            for (int cf = 0; cf < 4; ++cf) {
                int col = wave * 64 + cf * 16 + lr;
                float v = acc[rf][cf][r] + (float)bias[col];
                size_t off = (size_t)row * 256 + col;
                if (out_f32) ((float*)outv)[off] = v;
                else         ((bf16*)outv)[off]  = (bf16)v;
            }
        }
    }
}

// ---------------- GEMM tile (bf16 A): 64 rows x 256 cols / block ----------------
// out[r,c] = (A@W)[r,c] (*dinv[r]) (+bias[c]) (relu), bf16
__global__ __launch_bounds__(256) void gemm_tile(const bf16* __restrict__ A,
                                                 const bf16* __restrict__ Wpk,
                                                 int K,
                                                 const float* __restrict__ dinv,
                                                 const bf16* __restrict__ bias,
                                                 int relu,
                                                 bf16* __restrict__ out) {
    int wave = threadIdx.x >> 6;
    int lane = threadIdx.x & 63;
    int row0 = blockIdx.x * 64;
    int lr = lane & 15;
    int lk = (lane >> 4) * 8;

    int arow[4];
#pragma unroll
    for (int rf = 0; rf < 4; ++rf) {
        int r = row0 + rf * 16 + lr;
        arow[rf] = r < NODES ? r : (NODES - 1);
    }

    f32x4 acc[4][4];
    f32x4 z = {0.f, 0.f, 0.f, 0.f};
#pragma unroll
    for (int i = 0; i < 4; ++i)
#pragma unroll
        for (int j = 0; j < 4; ++j) acc[i][j] = z;

    int ktiles = K >> 5;
    for (int kt = 0; kt < ktiles; ++kt) {
        const bf16* Ab = A + kt * 32 + lk;
        bf16x8 af[4];
#pragma unroll
        for (int rf = 0; rf < 4; ++rf)
            af[rf] = *(const bf16x8*)(Ab + (size_t)arow[rf] * K);
        const bf16* wb = Wpk + ((size_t)(kt * 16 + wave * 4) * 64 + lane) * 8;
        bf16x8 bfv[4];
#pragma unroll
        for (int cf = 0; cf < 4; ++cf)
            bfv[cf] = *(const bf16x8*)(wb + cf * 512);
#pragma unroll
        for (int rf = 0; rf < 4; ++rf)
#pragma unroll
            for (int cf = 0; cf < 4; ++cf)
                acc[rf][cf] = __builtin_amdgcn_mfma_f32_16x16x32_bf16(
                    af[rf], bfv[cf], acc[rf][cf], 0, 0, 0);
    }

    int rb = (lane >> 4) * 4;
#pragma unroll
    for (int rf = 0; rf < 4; ++rf) {
#pragma unroll
        for (int r = 0; r < 4; ++r) {
            int row = row0 + rf * 16 + rb + r;
            if (row >= NODES) continue;
            float s = dinv ? dinv[row] : 1.0f;
#pragma unroll
            for (int cf = 0; cf < 4; ++cf) {
                int col = wave * 64 + cf * 16 + lr;
                float v = acc[rf][cf][r] * s;
                if (bias) v += (float)bias[col];
                if (relu) v = fmaxf(v, 0.0f);
                out[(size_t)row * 256 + col] = (bf16)v;
            }
        }
    }
}

// ---------------- gather1: 128-feat rows, one wave/node, x8 MLP ----------------
// aggX[n] = dinv[n] * (sum_{s in N(n)} Xs[s] + Xs[n])     (bf16)
__global__ __launch_bounds__(256) void gather1(const int* __restrict__ col_ptr,
                                               const int* __restrict__ col_idx,
                                               const bf16* __restrict__ Xs,
                                               const float* __restrict__ dinv,
                                               bf16* __restrict__ aggX) {
    int wid  = (int)((blockIdx.x * 256 + threadIdx.x) >> 6);
    int lane = threadIdx.x & 63;
    if (wid >= NODES) return;
    int beg = col_ptr[wid], end = col_ptr[wid + 1];
    int c2 = lane * 2;

    float a0 = 0.f, a1 = 0.f;
    for (int chunk = beg; chunk < end; chunk += 64) {
        int cnt = end - chunk;
        if (cnt > 64) cnt = 64;
        int myidx = (lane < cnt) ? col_idx[chunk + lane] : 0;
        int j = 0;
        for (; j + 8 <= cnt; j += 8) {
            bf16x2 v[8];
#pragma unroll
            for (int u = 0; u < 8; ++u) {
                int s = __shfl(myidx, j + u);
                v[u] = *(const bf16x2*)(Xs + (size_t)s * FIN + c2);
            }
#pragma unroll
            for (int u = 0; u < 8; ++u) { a0 += (float)v[u][0]; a1 += (float)v[u][1]; }
        }
        for (; j < cnt; ++j) {
            int s = __shfl(myidx, j);
            bf16x2 v = *(const bf16x2*)(Xs + (size_t)s * FIN + c2);
            a0 += (float)v[0]; a1 += (float)v[1];
        }
    }

    bf16x2 self = *(const bf16x2*)(Xs + (size_t)wid * FIN + c2);
    float di = dinv[wid];
    bf16x2 o;
    o[0] = (bf16)(di * (a0 + (float)self[0]));
    o[1] = (bf16)(di * (a1 + (float)self[1]));
    *(bf16x2*)(aggX + (size_t)wid * FIN + c2) = o;
}

// ---------------- gather2: 256-feat rows, x8 MLP, fused epilogue ----------------
// out[n] = relu(dinv[n]*(sum Y2[s] + Y2[n]) + b2 + proj[n])
__global__ __launch_bounds__(256) void gather2(const int* __restrict__ col_ptr,
                                               const int* __restrict__ col_idx,
                                               const bf16* __restrict__ Y2,
                                               const float* __restrict__ dinv,
                                               const bf16* __restrict__ bias,
                                               const void* __restrict__ proj,
                                               void* __restrict__ outv,
                                               const int* __restrict__ flags) {
    int io_f32 = (flags[0] == 0);
    int wid  = (int)((blockIdx.x * 256 + threadIdx.x) >> 6);
    int lane = threadIdx.x & 63;
    if (wid >= NODES) return;
    int beg = col_ptr[wid], end = col_ptr[wid + 1];
    int c = lane * 4;

    f32x4 acc = {0.f, 0.f, 0.f, 0.f};
    for (int chunk = beg; chunk < end; chunk += 64) {
        int cnt = end - chunk;
        if (cnt > 64) cnt = 64;
        int myidx = (lane < cnt) ? col_idx[chunk + lane] : 0;
        int j = 0;
        for (; j + 8 <= cnt; j += 8) {
            bf16x4 v[8];
#pragma unroll
            for (int u = 0; u < 8; ++u) {
                int s = __shfl(myidx, j + u);
                v[u] = *(const bf16x4*)(Y2 + (size_t)s * 256 + c);
            }
#pragma unroll
            for (int u = 0; u < 8; ++u)
#pragma unroll
                for (int k = 0; k < 4; ++k) acc[k] += (float)v[u][k];
        }
        for (; j < cnt; ++j) {
            int s = __shfl(myidx, j);
            bf16x4 v = *(const bf16x4*)(Y2 + (size_t)s * 256 + c);
#pragma unroll
            for (int k = 0; k < 4; ++k) acc[k] += (float)v[k];
        }
    }

    bf16x4 selfv = *(const bf16x4*)(Y2 + (size_t)wid * 256 + c);
    float di = dinv[wid];
    size_t base = (size_t)wid * 256 + c;

    f32x4 res;
#pragma unroll
    for (int k = 0; k < 4; ++k)
        res[k] = di * (acc[k] + (float)selfv[k]) + (float)bias[c + k];

    if (io_f32) {
        f32x4 pv = *(const f32x4*)((const float*)proj + base);
        f32x4 o;
#pragma unroll
        for (int k = 0; k < 4; ++k) o[k] = fmaxf(res[k] + pv[k], 0.0f);
        *(f32x4*)((float*)outv + base) = o;
    } else {
        bf16x4 pv = *(const bf16x4*)((const bf16*)proj + base);
        bf16x4 o;
#pragma unroll
        for (int k = 0; k < 4; ++k) o[k] = (bf16)fmaxf(res[k] + (float)pv[k], 0.0f);
        *(bf16x4*)((bf16*)outv + base) = o;
    }
}

__global__ __launch_bounds__(256) void zero_out(bf16* out, int nelem) {
    int i = blockIdx.x * 256 + threadIdx.x;
    if (i < nelem) out[i] = (bf16)0.0f;
}

extern "C" void kernel_launch(void* const* d_in, const int* in_sizes, int n_in,
                              void* d_out, int out_size, void* d_ws, size_t ws_size,
                              hipStream_t stream) {
    const void* x   = d_in[0];
    const int*  ei  = (const int*)d_in[1];
    const void* W1  = d_in[2];
    const void* b1  = d_in[3];
    const void* W2  = d_in[4];
    const void* b2  = d_in[5];
    const void* Wp  = d_in[6];
    const void* bp  = d_in[7];

    const size_t NEEDED = 401408ull * 3 + 1024ull * 4 + 6400000 + 65536 + 131072 + 65536
                        + 1536 + 25600000ull * 2 + 51200000ull;  // ~110.3 MB (known fit)
    if (ws_size < NEEDED) {
        zero_out<<<(NODES * 256 + 255) / 256, 256, 0, stream>>>((bf16*)d_out, NODES * 256);
        return;
    }
    char* w = (char*)d_ws;
    int*   col_ptr = (int*)w;   w += 401408;     // N+1 ints
    int*   deg     = (int*)w;   w += 401408;     // degree (memset with bhist)
    int*   bhist   = (int*)w;   w += 1024;       // 196 ints (contiguous after deg)
    float* dinv    = (float*)w; w += 401408;
    int*   blk     = (int*)w;   w += 1024;
    int*   flags   = (int*)w;   w += 1024;
    int*   bbase   = (int*)w;   w += 1024;       // 197 ints
    int*   bcur    = (int*)w;   w += 1024;
    int*   col_idx = (int*)w;   w += 6400000;    // E ints
    bf16*  W1p     = (bf16*)w;  w += 65536;
    bf16*  W2p     = (bf16*)w;  w += 131072;
    bf16*  Wpp     = (bf16*)w;  w += 65536;
    bf16*  b1b     = (bf16*)w;  w += 512;
    bf16*  b2b     = (bf16*)w;  w += 512;
    bf16*  bpb     = (bf16*)w;  w += 512;
    bf16*  Xs      = (bf16*)w;  w += 25600000;   // dinv*x (N x 128); pairs overlaid pre-GEMM
    bf16*  aggX    = (bf16*)w;  w += 25600000;   // S*x (N x 128)
    bf16*  H1      = (bf16*)w;  w += 51200000;   // relu(conv1) (N x 256)
    uint2* pairs   = (uint2*)Xs;                 // E pairs (12.8 MB), dead before Xs written
    bf16*  Y2      = Xs;                         // dinv*(H1@W2) overlays Xs+aggX (51.2 MB)

    const int NBLK = (NODES + 1 + 1023) / 1024;  // 98

    // 0) detect dtypes
    detect_kernel<<<1, 256, 0, stream>>>(x, ei, flags);

    // 1) degree + bucket histogram -> dinv
    hipMemsetAsync(deg, 0, 401408 + 1024, stream);
    deg_count<<<(EDGES + 511) / 512, 512, 0, stream>>>(ei, deg, bhist, flags);
    deg_to_dinv<<<(NODES + 255) / 256, 256, 0, stream>>>(deg, dinv, NODES);

    // 2) col_ptr scan + bucket scan
    scan1<<<NBLK, 1024, 0, stream>>>(deg, col_ptr, blk, NODES);
    scan2<<<1, 128, 0, stream>>>(blk, NBLK);
    scan3<<<(NODES + 256) / 256, 256, 0, stream>>>(col_ptr, blk, NODES);
    bucket_scan<<<1, 256, 0, stream>>>(bhist, bbase, bcur);

    // 3) CSR build: LDS-binned partition + per-bucket fine fill (write-amp ~1x)
    partition_edges<<<(EDGES + EPB - 1) / EPB, 256, 0, stream>>>(ei, bcur, pairs, flags);
    fine_fill<<<NBUCK, 512, 0, stream>>>(pairs, bbase, col_ptr, col_idx);

    // 4) pack weights + biases
    pack_all<<<515, 256, 0, stream>>>(W1, W2, Wp, b1, b2, bp,
                                      W1p, W2p, Wpp, b1b, b2b, bpb, flags);

    const int gemm_grid   = (NODES + 63) / 64;
    const int gather_grid = (NODES + 3) / 4;

    // 5) proj -> d_out, and emit Xs = dinv*x (overwrites pairs; stream-ordered after fine_fill)
    gemm_proj<<<gemm_grid, 256, 0, stream>>>(x, Wpp, dinv, bpb, d_out, Xs, flags);
    // 6) gather1 on 128-feat rows: aggX = dinv*(sum Xs + self)
    gather1<<<gather_grid, 256, 0, stream>>>(col_ptr, col_idx, Xs, dinv, aggX);
    // 7) conv1 GEMM: H1 = relu(aggX@W1 + b1)
    gemm_tile<<<gemm_grid, 256, 0, stream>>>(aggX, W1p, FIN, nullptr, b1b, 1, H1);
    // 8) conv2 GEMM: Y2 = dinv*(H1@W2)   (Y2 overlays dead Xs+aggX)
    gemm_tile<<<gemm_grid, 256, 0, stream>>>(H1, W2p, FOUT, dinv, nullptr, 0, Y2);
    // 9) gather2: d_out = relu(dinv*(sum Y2 + self) + b2 + proj)
    gather2<<<gather_grid, 256, 0, stream>>>(col_ptr, col_idx, Y2, dinv, b2b,
                                             d_out, d_out, flags);
}